// Round 5
// baseline (23.182 us; speedup 1.0000x reference)
//
#include <hip/hip_runtime.h>
#include <math.h>

#define NVOICE 8
#define NPROF  16
#define NHARM  64
#define NFRAME 64
#define NSAMP  16384
#define NB     16

// Only harmonics h in [0,15] can ever have freq < 1.0.  For h >= 16,
// base*(h+1)^2 >= MIN_FREQ*289 = 1.048 > 1 for every frame, so freq clips
// to exactly 1.0, the phase prefix is an even integer, S is an integer,
// and sin(pi*S) == 0 exactly: those rows contribute nothing.
#define NKEEP  16
#define NROWS2 (NVOICE * NKEEP)        // 128 rows per batch

// MIN_FREQ = FREQ_INTERVAL = 40 / 11025
__device__ __forceinline__ float min_freq() { return 40.0f / 11025.0f; }

// ---------------------------------------------------------------------------
// Phase A: per (b, v, frame) compute frame-rate freq/amp for rows h=0..15,
// then per-row frame prefix of the cumsum via a 64-lane f64 shfl scan.
// Stored HALVED: Fws = F/2, Aws = amp, Pws = (prefix/2) mod 1.
// ws layout (floats): X[b][frame][row], row = v*16 + h.
// ---------------------------------------------------------------------------
__global__ __launch_bounds__(64)
void hm_phaseA(const float* __restrict__ f0,
               const float* __restrict__ harm,
               const float* __restrict__ prof,
               float* __restrict__ Fws,
               float* __restrict__ Aws,
               float* __restrict__ Pws)
{
    const int blk = blockIdx.x;          // 0..127 = b*8 + v
    const int b = blk >> 3, v = blk & 7;
    const int f = threadIdx.x;           // frame 0..63

    __shared__ float profl[NPROF][NKEEP];
    __shared__ float Fl[NKEEP][NFRAME];     // unhalved freqs for scan

    for (int t = f; t < NPROF * NKEEP; t += 64) {
        const int p = t >> 4, c = t & 15;
        profl[p][c] = prof[p * NHARM + c];
    }

    const float re   = f0[((size_t)b * 16 + 2 * v    ) * NFRAME + f];
    const float im   = f0[((size_t)b * 16 + 2 * v + 1) * NFRAME + f];
    const float amp0 = re * re + im * im;
    const float ang  = atan2f(im, re) * 0.3183098861837907f;  // /pi
    const float base = min_freq() + ang * ang * min_freq();

    // softmax over 16 profiles for this (b,v,f)
    float w[NPROF];
    float m = -INFINITY;
#pragma unroll
    for (int p = 0; p < NPROF; ++p) {
        w[p] = harm[((size_t)b * (NVOICE * NPROF) + v * NPROF + p) * NFRAME + f];
        m = fmaxf(m, w[p]);
    }
    float s = 0.0f;
#pragma unroll
    for (int p = 0; p < NPROF; ++p) { w[p] = expf(w[p] - m); s += w[p]; }
    const float inv = 1.0f / s;
#pragma unroll
    for (int p = 0; p < NPROF; ++p) w[p] *= inv;

    __syncthreads();   // profl ready

    const int rowbase = v * NKEEP;
    float* Fo = Fws + ((size_t)b * NFRAME + f) * NROWS2 + rowbase;
    float* Ao = Aws + ((size_t)b * NFRAME + f) * NROWS2 + rowbase;

    // row 0: fundamental (never clipped)
    Fo[0] = 0.5f * base; Ao[0] = amp0; Fl[0][f] = base;

    // rows 1..15: harmonics; ratio = (h+1)^2
#pragma unroll
    for (int h = 1; h < NKEEP; ++h) {
        const float r  = (float)((h + 1) * (h + 1));
        const float Fv = fminf(base * r, 1.0f);
        float ha = 0.0f;
#pragma unroll
        for (int p = 0; p < NPROF; ++p) ha = fmaf(w[p], profl[p][h - 1], ha);
        ha = fminf(fmaxf(ha, 0.0f), 1.0f) * amp0;
        Fo[h] = 0.5f * Fv; Ao[h] = ha; Fl[h][f] = Fv;
    }
    __syncthreads();

    // Parallel prefix per row (halved units):
    //   term_0 = 64*F_0;  term_k = 64*(F_{k-1}+F_k);  P_k = frac(sum terms)
    // 64-lane inclusive Hillis-Steele scan in f64 (exact here).
    float* Po = Pws + ((size_t)b * NFRAME + f) * NROWS2 + rowbase;
#pragma unroll 4
    for (int h = 0; h < NKEEP; ++h) {
        const float Fc = Fl[h][f];
        const float Fm = (f > 0) ? Fl[h][f - 1] : 0.0f;
        double term = 64.0 * ((double)Fm + (double)Fc);   // f==0: 64*F_0
#pragma unroll
        for (int off = 1; off < 64; off <<= 1) {
            const double up = __shfl_up(term, off, 64);
            if (f >= off) term += up;
        }
        Po[h] = (float)(term - floor(term));
    }
}

// ---------------------------------------------------------------------------
// Phase B: 256-thread block = (batch, pair of 256-sample chunks).
// Wave w (0..3) owns (chunk q = w>>1, half h = w&1): all its LDS reads are
// wave-uniform broadcasts and all segment branches are wave-uniform.
// Each thread computes 2 samples (s = h*128 + l + {0,64}) sharing one
// {F2,dF2,A,dA,P2} row record -> 2 LDS reads feed 2 evals (ILP 2).
//   in-segment j = low ? s+128 : s-128
//   S/2 = P2 + t1*F2 + t2*dF2,  t1=j+1, t2=(j+1)^2/512
//   fa  = A + t3*dA,            t3=(j+0.5)/256
//   sin(pi*S) = v_sin_f32(fract(S/2))   [v_sin takes revolutions]
// Head chunk (c==0, low half) is flat: override t1 = s+1 (P=0, dF=0 staged).
// Tail (c==63, high) needs no override: t1=j+1 == s-127 already, dF=dA=0.
// ---------------------------------------------------------------------------
__global__ __launch_bounds__(256)
void hm_phaseB(const float* __restrict__ Fws,
               const float* __restrict__ Aws,
               const float* __restrict__ Pws,
               float* __restrict__ out)
{
    const int blk = blockIdx.x;          // 0..511
    const int b   = blk >> 5;
    const int cb  = blk & 31;            // chunk pair
    const int tid = threadIdx.x;

    __shared__ float4 cf[2][2][NROWS2];  // [q][half] {F2, dF2, A, dA}
    __shared__ float  pf[2][2][NROWS2];  // [q][half] P2

    // Staging: threads 0..127 stage chunk q=0, threads 128..255 stage q=1.
    {
        const int sq = tid >> 7;
        const int r  = tid & 127;
        const int cc = cb * 2 + sq;
        const int fm1 = (cc > 0)  ? cc - 1 : 0;
        const int fp1 = (cc < 63) ? cc + 1 : 63;
        const float* Fb = Fws + (size_t)b * NFRAME * NROWS2;
        const float* Ab = Aws + (size_t)b * NFRAME * NROWS2;
        const float* Pb = Pws + (size_t)b * NFRAME * NROWS2;
        const float Fm = Fb[(size_t)fm1 * NROWS2 + r];
        const float Fc = Fb[(size_t)cc  * NROWS2 + r];
        const float Fp = Fb[(size_t)fp1 * NROWS2 + r];
        const float Am = Ab[(size_t)fm1 * NROWS2 + r];
        const float Ac = Ab[(size_t)cc  * NROWS2 + r];
        const float Ap = Ab[(size_t)fp1 * NROWS2 + r];
        cf[sq][0][r] = make_float4(Fm, Fc - Fm, Am, Ac - Am);
        cf[sq][1][r] = make_float4(Fc, Fp - Fc, Ac, Ap - Ac);
        pf[sq][0][r] = (cc == 0) ? 0.0f : Pb[(size_t)(cc - 1) * NROWS2 + r];
        pf[sq][1][r] = Pb[(size_t)cc * NROWS2 + r];
    }
    __syncthreads();

    const int q = tid >> 7;              // chunk within pair (wave-uniform)
    const int h = (tid >> 6) & 1;        // segment half (wave-uniform)
    const int l = tid & 63;
    const int c = cb * 2 + q;

    const int j0 = l + (h ? 0 : 128);    // in-segment sample index, k=0
    const int j1 = j0 + 64;

    float t1a = (float)(j0 + 1);
    float t1b = (float)(j1 + 1);
    const float t2a = (float)((j0 + 1) * (j0 + 1)) * (1.0f / 512.0f);
    const float t2b = (float)((j1 + 1) * (j1 + 1)) * (1.0f / 512.0f);
    const float t3a = ((float)j0 + 0.5f) * (1.0f / 256.0f);
    const float t3b = ((float)j1 + 0.5f) * (1.0f / 256.0f);
    if (c == 0 && h == 0) {              // flat head: S = (s+1)*F0
        t1a = (float)(l + 1);
        t1b = (float)(l + 65);
    }

    const float4* __restrict__ V = cf[q][h];
    const float*  __restrict__ P = pf[q][h];

    float acc0 = 0.0f, acc1 = 0.0f;
#pragma unroll 4
    for (int r = 0; r < NROWS2; ++r) {
        const float4 vv = V[r];
        const float  pp = P[r];
        const float x0 = fmaf(t2a, vv.y, fmaf(t1a, vv.x, pp));
        const float x1 = fmaf(t2b, vv.y, fmaf(t1b, vv.x, pp));
        const float fa0 = fmaf(t3a, vv.w, vv.z);
        const float fa1 = fmaf(t3b, vv.w, vv.z);
        acc0 = fmaf(fa0, __builtin_amdgcn_sinf(__builtin_amdgcn_fractf(x0)), acc0);
        acc1 = fmaf(fa1, __builtin_amdgcn_sinf(__builtin_amdgcn_fractf(x1)), acc1);
    }

    float* o = out + (size_t)b * NSAMP + c * 256 + h * 128 + l;
    o[0]  = acc0;
    o[64] = acc1;
}

// ---------------------------------------------------------------------------
extern "C" void kernel_launch(void* const* d_in, const int* in_sizes, int n_in,
                              void* d_out, int out_size, void* d_ws, size_t ws_size,
                              hipStream_t stream)
{
    const float* f0   = (const float*)d_in[0];   // (16, 16, 64)
    const float* harm = (const float*)d_in[1];   // (16, 128, 64)
    const float* prof = (const float*)d_in[2];   // (16, 64)

    const size_t plane = (size_t)NB * NFRAME * NROWS2;   // 131072 floats
    float* Fws = (float*)d_ws;
    float* Aws = Fws + plane;
    float* Pws = Aws + plane;

    hm_phaseA<<<NB * NVOICE, 64, 0, stream>>>(f0, harm, prof, Fws, Aws, Pws);
    hm_phaseB<<<NB * 32, 256, 0, stream>>>(Fws, Aws, Pws, (float*)d_out);
}

// Round 6
// 18.012 us; speedup vs baseline: 1.2871x; 1.2871x over previous
//
#include <hip/hip_runtime.h>
#include <math.h>

#define NVOICE 8
#define NPROF  16
#define NHARM  64
#define NFRAME 64
#define NSAMP  16384
#define NB     16

// Only harmonics h in [0,15] can ever have freq < 1.0.  For h >= 16,
// base*(h+1)^2 >= MIN_FREQ*289 = 1.048 > 1 for every frame, so freq clips
// to exactly 1.0, the phase prefix is an even integer, S is an integer,
// and sin(pi*S) == 0 exactly: those rows contribute nothing.
#define NKEEP  16
#define NROWS2 (NVOICE * NKEEP)        // 128 rows per batch

// MIN_FREQ = FREQ_INTERVAL = 40 / 11025
__device__ __forceinline__ float min_freq() { return 40.0f / 11025.0f; }

// ---------------------------------------------------------------------------
// Fully fused kernel: one 256-thread block per (batch, pair of 256-sample
// chunks c0=2cb, c1=2cb+1).  Each block recomputes the frame-rate model for
// its own needs:
//   - base[v][k] for all 64 frames (needed for the phase prefix), from f0
//   - per-row phase prefix P (f64 serial chain over <=c1+1 frames, reading
//     base from LDS; dependent op is a ~4cyc f64 add, not a shfl chain)
//   - softmax/amps at ONLY the 4 frames {c0-1, c0, c1, c1+1} this pair uses
// Then the sample loop (identical math to the previous phaseB):
//   S/2 = P2 + t1*F2 + t2*dF2,  t1=j+1, t2=(j+1)^2/512,  fa = A + t3*dA
//   sin(pi*S) = v_sin_f32(fract(S/2))   [v_sin takes revolutions]
// Wave w (0..3) owns (chunk q=w>>1, half h=w&1): LDS reads in the main loop
// are wave-uniform broadcasts; head/tail branches are wave-uniform.
// Each thread computes 2 samples sharing one row record.
// ---------------------------------------------------------------------------
__global__ __launch_bounds__(256)
void hm_fused(const float* __restrict__ f0,
              const float* __restrict__ harm,
              const float* __restrict__ prof,
              float* __restrict__ out)
{
    const int blk = blockIdx.x;          // 0..511
    const int b   = blk >> 5;
    const int cb  = blk & 31;
    const int c0  = cb * 2, c1 = c0 + 1;
    const int tid = threadIdx.x;

    __shared__ float  sBase[NVOICE][NFRAME + 1];   // +1 pad: conflict-free scan
    __shared__ float  sAmp0[NVOICE][NFRAME + 1];
    __shared__ float  sProf[NPROF][NKEEP];         // prof[p][0..14]
    __shared__ float  sW[NVOICE][4][NPROF];        // softmax at the 4 frames
    __shared__ float  sP[3][NROWS2];               // P2 at frames {c0-1,c0,c1}
    __shared__ float  sA[4][NROWS2];               // amps at the 4 frames
    __shared__ float4 cf[2][2][NROWS2];            // [q][half] {F2,dF2,A,dA}
    __shared__ float  pf[2][2][NROWS2];            // [q][half] P2

    // ---- step 1: stage prof; compute base & amp0 for all (v, k) ----------
    if (tid < NPROF * NKEEP)
        sProf[tid >> 4][tid & 15] = prof[(tid >> 4) * NHARM + (tid & 15)];

    for (int idx = tid; idx < NVOICE * NFRAME; idx += 256) {
        const int v = idx >> 6, k = idx & 63;
        const float re  = f0[((size_t)b * 16 + 2 * v    ) * NFRAME + k];
        const float im  = f0[((size_t)b * 16 + 2 * v + 1) * NFRAME + k];
        const float ang = atan2f(im, re) * 0.3183098861837907f;   // /pi
        sBase[v][k] = min_freq() + ang * ang * min_freq();
        sAmp0[v][k] = re * re + im * im;
    }
    __syncthreads();

    // ---- step 2: phase-prefix scan (waves 0,1)  ||  softmax (wave 2) -----
    if (tid < NROWS2) {
        // row r = v*16 + h; serial f64 chain over frames 0..c1 (<=64 iters).
        // term_0 = 64*F_0; term_k = 64*(F_{k-1}+F_k); P2_k = frac(sum).
        const int r = tid, v = r >> 4, h = r & 15;
        const float r2 = (float)((h + 1) * (h + 1));
        double p = 0.0;
        float prevF = 0.0f;
        for (int k = 0; k <= c1; ++k) {
            const float F = fminf(sBase[v][k] * r2, 1.0f);
            p += 64.0 * (double)(prevF + F);     // k==0: 64*F_0
            prevF = F;
            if (k == c0 - 1) sP[0][r] = (float)(p - floor(p));
            if (k == c0)     sP[1][r] = (float)(p - floor(p));
            if (k == c1)     sP[2][r] = (float)(p - floor(p));
        }
    } else if (tid < 128 + 32) {
        // 32 softmaxes: (v, fi) over the 4 needed frames
        const int t2 = tid - 128;
        const int v = t2 >> 2, fi = t2 & 3;
        const int f = min(max(c0 - 1 + fi, 0), 63);
        float w[NPROF];
        float m = -INFINITY;
#pragma unroll
        for (int p = 0; p < NPROF; ++p) {
            w[p] = harm[((size_t)b * (NVOICE * NPROF) + v * NPROF + p) * NFRAME + f];
            m = fmaxf(m, w[p]);
        }
        float s = 0.0f;
#pragma unroll
        for (int p = 0; p < NPROF; ++p) { w[p] = expf(w[p] - m); s += w[p]; }
        const float inv = 1.0f / s;
#pragma unroll
        for (int p = 0; p < NPROF; ++p) sW[v][fi][p] = w[p] * inv;
    }
    __syncthreads();

    // ---- step 3: amplitudes at the 4 frames (512 values, 2/thread) -------
    for (int idx = tid; idx < 4 * NROWS2; idx += 256) {
        const int fi = idx >> 7, r = idx & 127, v = r >> 4, h = r & 15;
        const int f = min(max(c0 - 1 + fi, 0), 63);
        const float a0 = sAmp0[v][f];
        float A = a0;                            // h==0: fundamental
        if (h != 0) {
            float d = 0.0f;
#pragma unroll
            for (int p = 0; p < NPROF; ++p) d = fmaf(sW[v][fi][p], sProf[p][h - 1], d);
            A = fminf(fmaxf(d, 0.0f), 1.0f) * a0;
        }
        sA[fi][r] = A;
    }
    __syncthreads();

    // ---- step 4: build per-(chunk,half) row records -----------------------
    for (int idx = tid; idx < 4 * NROWS2; idx += 256) {
        const int qh = idx >> 7, r = idx & 127;      // qh = q*2 + hh
        const int q = qh >> 1, hh = qh & 1;
        const int v = r >> 4, h = r & 15;
        const float r2 = (float)((h + 1) * (h + 1));
        const int fiA = q + hh, fiB = fiA + 1;
        const int fA = min(max(c0 - 1 + fiA, 0), 63);
        const int fB = min(max(c0 - 1 + fiB, 0), 63);
        const float Fa = 0.5f * fminf(sBase[v][fA] * r2, 1.0f);
        const float Fb = 0.5f * fminf(sBase[v][fB] * r2, 1.0f);
        const float Aa = sA[fiA][r], Ab = sA[fiB][r];
        cf[q][hh][r] = make_float4(Fa, Fb - Fa, Aa, Ab - Aa);
        pf[q][hh][r] = (hh == 0) ? ((c0 + q == 0) ? 0.0f : sP[q][r])
                                 : sP[q + 1][r];
    }
    __syncthreads();

    // ---- step 5: sample synthesis (identical to previous phaseB) ---------
    const int q = tid >> 7;              // chunk within pair (wave-uniform)
    const int h = (tid >> 6) & 1;        // segment half (wave-uniform)
    const int l = tid & 63;
    const int c = c0 + q;

    const int j0 = l + (h ? 0 : 128);    // in-segment sample index
    const int j1 = j0 + 64;

    float t1a = (float)(j0 + 1);
    float t1b = (float)(j1 + 1);
    const float t2a = (float)((j0 + 1) * (j0 + 1)) * (1.0f / 512.0f);
    const float t2b = (float)((j1 + 1) * (j1 + 1)) * (1.0f / 512.0f);
    const float t3a = ((float)j0 + 0.5f) * (1.0f / 256.0f);
    const float t3b = ((float)j1 + 0.5f) * (1.0f / 256.0f);
    if (c == 0 && h == 0) {              // flat head: S = (s+1)*F0
        t1a = (float)(l + 1);
        t1b = (float)(l + 65);
    }

    const float4* __restrict__ V = cf[q][h];
    const float*  __restrict__ P = pf[q][h];

    float acc0 = 0.0f, acc1 = 0.0f;
#pragma unroll 4
    for (int r = 0; r < NROWS2; ++r) {
        const float4 vv = V[r];
        const float  pp = P[r];
        const float x0 = fmaf(t2a, vv.y, fmaf(t1a, vv.x, pp));
        const float x1 = fmaf(t2b, vv.y, fmaf(t1b, vv.x, pp));
        const float fa0 = fmaf(t3a, vv.w, vv.z);
        const float fa1 = fmaf(t3b, vv.w, vv.z);
        acc0 = fmaf(fa0, __builtin_amdgcn_sinf(__builtin_amdgcn_fractf(x0)), acc0);
        acc1 = fmaf(fa1, __builtin_amdgcn_sinf(__builtin_amdgcn_fractf(x1)), acc1);
    }

    float* o = out + (size_t)b * NSAMP + c * 256 + h * 128 + l;
    o[0]  = acc0;
    o[64] = acc1;
}

// ---------------------------------------------------------------------------
extern "C" void kernel_launch(void* const* d_in, const int* in_sizes, int n_in,
                              void* d_out, int out_size, void* d_ws, size_t ws_size,
                              hipStream_t stream)
{
    const float* f0   = (const float*)d_in[0];   // (16, 16, 64)
    const float* harm = (const float*)d_in[1];   // (16, 128, 64)
    const float* prof = (const float*)d_in[2];   // (16, 64)

    hm_fused<<<NB * 32, 256, 0, stream>>>(f0, harm, prof, (float*)d_out);
}

// Round 7
// 17.055 us; speedup vs baseline: 1.3592x; 1.0561x over previous
//
#include <hip/hip_runtime.h>
#include <math.h>

#define NVOICE 8
#define NPROF  16
#define NHARM  64
#define NFRAME 64
#define NSAMP  16384
#define NB     16

// Only harmonics h in [0,15] can ever have freq < 1.0.  For h >= 16,
// base*(h+1)^2 >= MIN_FREQ*289 = 1.048 > 1 for every frame, so freq clips
// to exactly 1.0, the phase prefix is an even integer, S is an integer,
// and sin(pi*S) == 0 exactly: those rows contribute nothing.
#define NKEEP  16
#define NROWS2 (NVOICE * NKEEP)        // 128 rows per batch

typedef float f32x2 __attribute__((ext_vector_type(2)));

// MIN_FREQ = FREQ_INTERVAL = 40 / 11025
__device__ __forceinline__ float min_freq() { return 40.0f / 11025.0f; }

// ---------------------------------------------------------------------------
// Fully fused kernel: one 512-thread block per (batch, quad of 256-sample
// chunks c0..c0+3).  Each block recomputes the frame-rate model it needs:
//   - base[v][k] for all frames 0..c0+3 (phase prefix needs the full past)
//   - per-row phase prefix P (f64 serial chain, reading base from LDS)
//   - softmax/amps at ONLY the 6 frames {c0-1 .. c0+4} this quad touches
// Then per-sample synthesis with f32x2-packed math (v_pk_fma_f32):
//   S/2 = P2 + t1*F2 + t2*dF2,  t1=j+1, t2=(j+1)^2/512,  fa = A + t3*dA
//   sin(pi*S) = v_sin_f32(fract(S/2))   [v_sin takes revolutions]
// Wave w (0..7) owns (chunk q=w>>1, half h=w&1): LDS reads in the main loop
// are wave-uniform broadcasts; head/tail branches are wave-uniform.
// Each thread computes 2 samples sharing one row record (packed as f32x2).
// ---------------------------------------------------------------------------
__global__ __launch_bounds__(512)
void hm_fused(const float* __restrict__ f0,
              const float* __restrict__ harm,
              const float* __restrict__ prof,
              float* __restrict__ out)
{
    const int blk = blockIdx.x;          // 0..255
    const int b   = blk >> 4;
    const int qd  = blk & 15;            // chunk quad
    const int c0  = qd * 4;
    const int c3  = c0 + 3;
    const int tid = threadIdx.x;         // 0..511

    __shared__ float  sBase[NVOICE][NFRAME + 1];   // +1 pad
    __shared__ float  sAmp0[NVOICE][NFRAME + 1];
    __shared__ float  sProf[NPROF][NKEEP];         // prof[p][0..14]
    __shared__ float  sW[NVOICE][6][NPROF];        // softmax at the 6 frames
    __shared__ float  sP[5][NROWS2];               // P2 at frames c0-1 .. c0+3
    __shared__ float  sA[6][NROWS2];               // amps at the 6 frames
    __shared__ float4 cf[4][2][NROWS2];            // [q][half] {F2,dF2,A,dA}
    __shared__ float  pf[4][2][NROWS2];            // [q][half] P2

    // ---- step 1: stage prof; base & amp0 for all (v, k) -------------------
    if (tid < NPROF * NKEEP)
        sProf[tid >> 4][tid & 15] = prof[(tid >> 4) * NHARM + (tid & 15)];

    if (tid < NVOICE * NFRAME) {
        const int v = tid >> 6, k = tid & 63;
        const float re  = f0[((size_t)b * 16 + 2 * v    ) * NFRAME + k];
        const float im  = f0[((size_t)b * 16 + 2 * v + 1) * NFRAME + k];
        const float ang = atan2f(im, re) * 0.3183098861837907f;   // /pi
        sBase[v][k] = min_freq() + ang * ang * min_freq();
        sAmp0[v][k] = re * re + im * im;
    }
    __syncthreads();

    // ---- step 2: phase-prefix scan (waves 0,1)  ||  softmax (wave 2) -----
    if (tid < NROWS2) {
        // row r = v*16 + h; serial f64 chain over frames 0..c3 (<=64 iters).
        // term_0 = 64*F_0; term_k = 64*(F_{k-1}+F_k); P2_k = frac(sum).
        const int r = tid, v = r >> 4, h = r & 15;
        const float r2 = (float)((h + 1) * (h + 1));
        if (c0 == 0) sP[0][r] = 0.0f;        // frame -1: prefix is 0
        double p = 0.0;
        float prevF = 0.0f;
        for (int k = 0; k <= c3; ++k) {
            const float F = fminf(sBase[v][k] * r2, 1.0f);
            p += 64.0 * (double)(prevF + F);     // k==0: 64*F_0
            prevF = F;
            const int fi = k - (c0 - 1);
            if (fi >= 0) sP[fi][r] = (float)(p - floor(p));  // fi<=4 by bound
        }
    } else if (tid < 128 + 48) {
        // 48 softmaxes: (v, fi) over the 6 needed frames
        const int t2 = tid - 128;
        const int v = t2 / 6, fi = t2 % 6;
        const int f = min(max(c0 - 1 + fi, 0), 63);
        float w[NPROF];
        float m = -INFINITY;
#pragma unroll
        for (int p = 0; p < NPROF; ++p) {
            w[p] = harm[((size_t)b * (NVOICE * NPROF) + v * NPROF + p) * NFRAME + f];
            m = fmaxf(m, w[p]);
        }
        float s = 0.0f;
#pragma unroll
        for (int p = 0; p < NPROF; ++p) { w[p] = expf(w[p] - m); s += w[p]; }
        const float inv = 1.0f / s;
#pragma unroll
        for (int p = 0; p < NPROF; ++p) sW[v][fi][p] = w[p] * inv;
    }
    __syncthreads();

    // ---- step 3: amplitudes at the 6 frames (768 values) ------------------
    for (int idx = tid; idx < 6 * NROWS2; idx += 512) {
        const int fi = idx >> 7, r = idx & 127, v = r >> 4, h = r & 15;
        const int f = min(max(c0 - 1 + fi, 0), 63);
        const float a0 = sAmp0[v][f];
        float A = a0;                            // h==0: fundamental
        if (h != 0) {
            float d = 0.0f;
#pragma unroll
            for (int p = 0; p < NPROF; ++p) d = fmaf(sW[v][fi][p], sProf[p][h - 1], d);
            A = fminf(fmaxf(d, 0.0f), 1.0f) * a0;
        }
        sA[fi][r] = A;
    }
    __syncthreads();

    // ---- step 4: build per-(chunk,half) row records (1024 of them) --------
    for (int idx = tid; idx < 8 * NROWS2; idx += 512) {
        const int qh = idx >> 7, r = idx & 127;      // qh = q*2 + hh
        const int q = qh >> 1, hh = qh & 1;
        const int v = r >> 4, h = r & 15;
        const float r2 = (float)((h + 1) * (h + 1));
        const int fiA = q + hh, fiB = fiA + 1;
        const int fA = min(max(c0 - 1 + fiA, 0), 63);
        const int fB = min(max(c0 - 1 + fiB, 0), 63);
        const float Fa = 0.5f * fminf(sBase[v][fA] * r2, 1.0f);
        const float Fb = 0.5f * fminf(sBase[v][fB] * r2, 1.0f);
        const float Aa = sA[fiA][r], Ab = sA[fiB][r];
        cf[q][hh][r] = make_float4(Fa, Fb - Fa, Aa, Ab - Aa);
        pf[q][hh][r] = hh ? sP[q + 1][r] : sP[q][r];   // sP[0]=0 when c0==0
    }
    __syncthreads();

    // ---- step 5: sample synthesis (f32x2-packed) --------------------------
    const int q = tid >> 7;              // chunk in quad (wave-uniform)
    const int h = (tid >> 6) & 1;        // segment half (wave-uniform)
    const int l = tid & 63;
    const int c = c0 + q;

    const int j0 = l + (h ? 0 : 128);    // in-segment sample index
    const int j1 = j0 + 64;

    f32x2 t1 = { (float)(j0 + 1), (float)(j1 + 1) };
    const f32x2 t2 = { (float)((j0 + 1) * (j0 + 1)) * (1.0f / 512.0f),
                       (float)((j1 + 1) * (j1 + 1)) * (1.0f / 512.0f) };
    const f32x2 t3 = { ((float)j0 + 0.5f) * (1.0f / 256.0f),
                       ((float)j1 + 0.5f) * (1.0f / 256.0f) };
    if (c == 0 && h == 0) {              // flat head: S = (s+1)*F0
        t1.x = (float)(l + 1);
        t1.y = (float)(l + 65);
    }

    const float4* __restrict__ V = cf[q][h];
    const float*  __restrict__ P = pf[q][h];

    f32x2 acc = { 0.0f, 0.0f };
#pragma unroll 4
    for (int r = 0; r < NROWS2; ++r) {
        const float4 vv = V[r];
        const float  pp = P[r];
        const f32x2 vF  = { vv.x, vv.x }, vdF = { vv.y, vv.y };
        const f32x2 vA  = { vv.z, vv.z }, vdA = { vv.w, vv.w };
        const f32x2 vP  = { pp, pp };
        const f32x2 x  = __builtin_elementwise_fma(t2, vdF,
                             __builtin_elementwise_fma(t1, vF, vP));
        const f32x2 fa = __builtin_elementwise_fma(t3, vdA, vA);
        const f32x2 sn = { __builtin_amdgcn_sinf(__builtin_amdgcn_fractf(x.x)),
                           __builtin_amdgcn_sinf(__builtin_amdgcn_fractf(x.y)) };
        acc = __builtin_elementwise_fma(fa, sn, acc);
    }

    float* o = out + (size_t)b * NSAMP + c * 256 + h * 128 + l;
    o[0]  = acc.x;
    o[64] = acc.y;
}

// ---------------------------------------------------------------------------
extern "C" void kernel_launch(void* const* d_in, const int* in_sizes, int n_in,
                              void* d_out, int out_size, void* d_ws, size_t ws_size,
                              hipStream_t stream)
{
    const float* f0   = (const float*)d_in[0];   // (16, 16, 64)
    const float* harm = (const float*)d_in[1];   // (16, 128, 64)
    const float* prof = (const float*)d_in[2];   // (16, 64)

    hm_fused<<<NB * 16, 512, 0, stream>>>(f0, harm, prof, (float*)d_out);
}

// Round 8
// 16.870 us; speedup vs baseline: 1.3742x; 1.0110x over previous
//
#include <hip/hip_runtime.h>
#include <math.h>

#define NVOICE 8
#define NPROF  16
#define NHARM  64
#define NFRAME 64
#define NSAMP  16384
#define NB     16

// Only harmonics h in [0,15] can ever have freq < 1.0.  For h >= 16,
// base*(h+1)^2 >= MIN_FREQ*289 = 1.048 > 1 for every frame, so freq clips
// to exactly 1.0, the phase prefix is an even integer, S is an integer,
// and sin(pi*S) == 0 exactly: those rows contribute nothing.
#define NKEEP  16
#define NROWS2 (NVOICE * NKEEP)        // 128 rows per batch

typedef float f32x2 __attribute__((ext_vector_type(2)));
typedef float f32x4 __attribute__((ext_vector_type(4)));

__device__ __forceinline__ float min_freq() { return 40.0f / 11025.0f; }
__device__ __forceinline__ f32x4 sp4(float s) { return (f32x4){s, s, s, s}; }

// ---------------------------------------------------------------------------
// Fully fused kernel: one 256-thread block per (batch, quad of 256-sample
// chunks c0..c0+3).  Front matter identical to R7 (re-strided for 256 thr):
//   base/amp0 for all frames, f64 serial phase prefix (128 rows in parallel),
//   softmax+amps at the 6 touched frames, per-(chunk,half) row records.
// Main loop: wave = one chunk; lanes 0-31 handle segment-half 0, lanes
// 32-63 half 1 (2-address LDS broadcast - free); each lane 4 samples.
// One ds_read_b128 + one shared ds_read_b64 (P paired) per 2 rows feeds
// 512 evals/wave -> LDS-pipe cost halved vs S=2 (the R7 bottleneck).
//   S/2 = P2 + t1*F2 + t2*dF2,  t1=j+1, t2=(j+1)^2/512,  fa = A + t3*dA
//   sin(pi*S) = v_sin_f32(fract(S/2))   [v_sin takes revolutions]
// ---------------------------------------------------------------------------
__global__ __launch_bounds__(256)
void hm_fused(const float* __restrict__ f0,
              const float* __restrict__ harm,
              const float* __restrict__ prof,
              float* __restrict__ out)
{
    const int blk = blockIdx.x;          // 0..255
    const int b   = blk >> 4;
    const int qd  = blk & 15;            // chunk quad
    const int c0  = qd * 4;
    const int c3  = c0 + 3;
    const int tid = threadIdx.x;         // 0..255

    __shared__ float  sBase[NVOICE][NFRAME + 1];   // +1 pad
    __shared__ float  sAmp0[NVOICE][NFRAME + 1];
    __shared__ float  sProf[NPROF][NKEEP];         // prof[p][0..14]
    __shared__ float  sW[NVOICE][6][NPROF];        // softmax at the 6 frames
    __shared__ float  sP[5][NROWS2];               // P2 at frames c0-1 .. c0+3
    __shared__ float  sA[6][NROWS2];               // amps at the 6 frames
    __shared__ float4 cf[4][2][NROWS2];            // [q][half] {F2,dF2,A,dA}
    __shared__ f32x2  pf2[4][2][NROWS2 / 2];       // [q][half] P2 pairs

    // ---- step 1: stage prof; base & amp0 for all (v, k) -------------------
    sProf[tid >> 4][tid & 15] = prof[(tid >> 4) * NHARM + (tid & 15)];

    for (int idx = tid; idx < NVOICE * NFRAME; idx += 256) {
        const int v = idx >> 6, k = idx & 63;
        const float re  = f0[((size_t)b * 16 + 2 * v    ) * NFRAME + k];
        const float im  = f0[((size_t)b * 16 + 2 * v + 1) * NFRAME + k];
        const float ang = atan2f(im, re) * 0.3183098861837907f;   // /pi
        sBase[v][k] = min_freq() + ang * ang * min_freq();
        sAmp0[v][k] = re * re + im * im;
    }
    __syncthreads();

    // ---- step 2: phase-prefix scan (threads 0-127) || softmax (128-175) ---
    if (tid < NROWS2) {
        // row r = v*16 + h; serial f64 chain over frames 0..c3 (<=64 iters).
        // term_0 = 64*F_0; term_k = 64*(F_{k-1}+F_k); P2_k = frac(sum).
        const int r = tid, v = r >> 4, h = r & 15;
        const float r2 = (float)((h + 1) * (h + 1));
        if (c0 == 0) sP[0][r] = 0.0f;        // frame -1: prefix is 0
        double p = 0.0;
        float prevF = 0.0f;
        for (int k = 0; k <= c3; ++k) {
            const float F = fminf(sBase[v][k] * r2, 1.0f);
            p += 64.0 * (double)(prevF + F);     // k==0: 64*F_0
            prevF = F;
            const int fi = k - (c0 - 1);
            if (fi >= 0) sP[fi][r] = (float)(p - floor(p));  // fi<=4 by bound
        }
    } else if (tid < 128 + 48) {
        // 48 softmaxes: (v, fi) over the 6 needed frames
        const int t2 = tid - 128;
        const int v = t2 / 6, fi = t2 % 6;
        const int f = min(max(c0 - 1 + fi, 0), 63);
        float w[NPROF];
        float m = -INFINITY;
#pragma unroll
        for (int p = 0; p < NPROF; ++p) {
            w[p] = harm[((size_t)b * (NVOICE * NPROF) + v * NPROF + p) * NFRAME + f];
            m = fmaxf(m, w[p]);
        }
        float s = 0.0f;
#pragma unroll
        for (int p = 0; p < NPROF; ++p) { w[p] = expf(w[p] - m); s += w[p]; }
        const float inv = 1.0f / s;
#pragma unroll
        for (int p = 0; p < NPROF; ++p) sW[v][fi][p] = w[p] * inv;
    }
    __syncthreads();

    // ---- step 3: amplitudes at the 6 frames (768 values) ------------------
    for (int idx = tid; idx < 6 * NROWS2; idx += 256) {
        const int fi = idx >> 7, r = idx & 127, v = r >> 4, h = r & 15;
        const int f = min(max(c0 - 1 + fi, 0), 63);
        const float a0 = sAmp0[v][f];
        float A = a0;                            // h==0: fundamental
        if (h != 0) {
            float d = 0.0f;
#pragma unroll
            for (int p = 0; p < NPROF; ++p) d = fmaf(sW[v][fi][p], sProf[p][h - 1], d);
            A = fminf(fmaxf(d, 0.0f), 1.0f) * a0;
        }
        sA[fi][r] = A;
    }
    __syncthreads();

    // ---- step 4: build per-(chunk,half) row records (1024 of them) --------
    for (int idx = tid; idx < 8 * NROWS2; idx += 256) {
        const int qh = idx >> 7, r = idx & 127;      // qh = q*2 + hh
        const int q = qh >> 1, hh = qh & 1;
        const int v = r >> 4, h = r & 15;
        const float r2 = (float)((h + 1) * (h + 1));
        const int fiA = q + hh, fiB = fiA + 1;
        const int fA = min(max(c0 - 1 + fiA, 0), 63);
        const int fB = min(max(c0 - 1 + fiB, 0), 63);
        const float Fa = 0.5f * fminf(sBase[v][fA] * r2, 1.0f);
        const float Fb = 0.5f * fminf(sBase[v][fB] * r2, 1.0f);
        const float Aa = sA[fiA][r], Ab = sA[fiB][r];
        cf[q][hh][r] = make_float4(Fa, Fb - Fa, Aa, Ab - Aa);
        ((float*)pf2[q][hh])[r] = hh ? sP[q + 1][r] : sP[q][r];  // sP[0]=0 if c0==0
    }
    __syncthreads();

    // ---- step 5: sample synthesis, S=4 per thread -------------------------
    // wave = chunk q; lanes 0-31: half 0 (samples 0-127, segment c-1),
    // lanes 32-63: half 1 (samples 128-255, segment c). Lane handles samples
    // s = (h?128:0) + l + {0,32,64,96}; in-segment j = s - (h?128:-128).
    const int q    = tid >> 6;           // chunk in quad (wave-uniform)
    const int lane = tid & 63;
    const int h    = lane >> 5;          // per-lane half
    const int l    = lane & 31;
    const int c    = c0 + q;

    f32x4 t1, t2, t3;
#pragma unroll
    for (int u = 0; u < 4; ++u) {
        const int j = l + 32 * u + (h ? 0 : 128);   // in-segment index
        float t1v = (float)(j + 1);
        if (c == 0 && h == 0) t1v = (float)(l + 32 * u + 1);  // flat head
        t1[u] = t1v;
        t2[u] = (float)((j + 1) * (j + 1)) * (1.0f / 512.0f);
        t3[u] = ((float)j + 0.5f) * (1.0f / 256.0f);
    }

    const float4* __restrict__ V  = cf[q][h];
    const f32x2*  __restrict__ Pp = pf2[q][h];

    f32x4 acc = {0.0f, 0.0f, 0.0f, 0.0f};
#pragma unroll 4
    for (int g = 0; g < NROWS2 / 2; ++g) {
        const f32x2  pp = Pp[g];
        const float4 v0 = V[2 * g];
        const float4 v1 = V[2 * g + 1];
        {
            const f32x4 x  = __builtin_elementwise_fma(t2, sp4(v0.y),
                                 __builtin_elementwise_fma(t1, sp4(v0.x), sp4(pp.x)));
            const f32x4 fa = __builtin_elementwise_fma(t3, sp4(v0.w), sp4(v0.z));
            const f32x4 sn = {
                __builtin_amdgcn_sinf(__builtin_amdgcn_fractf(x[0])),
                __builtin_amdgcn_sinf(__builtin_amdgcn_fractf(x[1])),
                __builtin_amdgcn_sinf(__builtin_amdgcn_fractf(x[2])),
                __builtin_amdgcn_sinf(__builtin_amdgcn_fractf(x[3])) };
            acc = __builtin_elementwise_fma(fa, sn, acc);
        }
        {
            const f32x4 x  = __builtin_elementwise_fma(t2, sp4(v1.y),
                                 __builtin_elementwise_fma(t1, sp4(v1.x), sp4(pp.y)));
            const f32x4 fa = __builtin_elementwise_fma(t3, sp4(v1.w), sp4(v1.z));
            const f32x4 sn = {
                __builtin_amdgcn_sinf(__builtin_amdgcn_fractf(x[0])),
                __builtin_amdgcn_sinf(__builtin_amdgcn_fractf(x[1])),
                __builtin_amdgcn_sinf(__builtin_amdgcn_fractf(x[2])),
                __builtin_amdgcn_sinf(__builtin_amdgcn_fractf(x[3])) };
            acc = __builtin_elementwise_fma(fa, sn, acc);
        }
    }

    float* o = out + (size_t)b * NSAMP + c * 256 + (h ? 128 : 0) + l;
    o[0]  = acc[0];
    o[32] = acc[1];
    o[64] = acc[2];
    o[96] = acc[3];
}

// ---------------------------------------------------------------------------
extern "C" void kernel_launch(void* const* d_in, const int* in_sizes, int n_in,
                              void* d_out, int out_size, void* d_ws, size_t ws_size,
                              hipStream_t stream)
{
    const float* f0   = (const float*)d_in[0];   // (16, 16, 64)
    const float* harm = (const float*)d_in[1];   // (16, 128, 64)
    const float* prof = (const float*)d_in[2];   // (16, 64)

    hm_fused<<<NB * 16, 256, 0, stream>>>(f0, harm, prof, (float*)d_out);
}